// Round 2
// baseline (27496.960 us; speedup 1.0000x reference)
//
#include <hip/hip_runtime.h>
#include <stdint.h>

// MultiRateLSTM on MI355X — persistent 16-WG kernel, dual-ring h exchange.
//
// v3: single-XCD fast channel with a PROVEN-safe fallback so no failure mode
// can hang.
//   - Election: 256 blocks launched; each reads HW_REG_XCC_ID (hwreg 20,
//     measured m09), claims a per-XCD ticket; first XCD with 16 claimants is
//     elected via CAS. Its 16 blocks become workers g=0..15, rest exit.
//   - FAST ring: sc0 stores + sc0 loads => both sides forced through the
//     XCD-local L2 (the coherence point for one XCD). ~250cy RT vs ~900+ for
//     the MALL path.
//   - SAFE ring: unconditional sc1 publish every step (v1-proven protocol).
//     Fast poll is bounded (FASTN ~ 1ms); on trip, the thread STICKILY falls
//     back to sc1 polling of the safe ring => broken-channel world finishes
//     at ~v1 speed instead of hanging.
//   - Tags are t+1 (never 0) so zero-poisoned workspace can't false-match at
//     t=1. Stale tags from prior launches carry identical data (deterministic
//     computation) => benign.
//   - 2-slot rings are safe: WG publishes t only after all WGs published t-1,
//     and within a step the poll precedes the publish, so no WG can still be
//     reading h(t-2) when slot t&1 is overwritten.
// Claim counters zeroed per launch by stream-ordered hipMemsetAsync (the
// harness's own reset() uses hipMemsetAsync, so it is graph-capture legal).
//
// 16 WGs x 256 threads. WG g owns hidden units [16g,16g+16). Wave w owns units
// 16g+4w..+3 x all 4 gates (16 MFMA cols). Weights live in VGPRs as f16 MFMA
// B-fragments (~152 regs/lane). Per step:
//   stage x -> LDS (overlaps h wait)
//   poll h(t-1) chunks (fast sc0 from XCD L2; sticky sc1 fallback) -> LDS
//   MFMA (2 accumulators) -> gate nonlinearities -> shfl gather -> c,h update
//   publish h(t) as {f16 h[2], u32 tag=t+1} chunks: sc0 (fast) + sc1 (safe)
//   store ys[t] fp32

typedef _Float16 half8 __attribute__((ext_vector_type(8)));
typedef float floatx4 __attribute__((ext_vector_type(4)));
typedef unsigned int u32x4 __attribute__((ext_vector_type(4)));

#define T_STEPS 8192
#define FASTN 4096   // ~1ms of fast polling before sticky fallback

__device__ __forceinline__ float fsig(float x) {
    return __builtin_amdgcn_rcpf(1.0f + __expf(-x));
}
__device__ __forceinline__ float ftanh(float x) {
    return 1.0f - 2.0f * __builtin_amdgcn_rcpf(1.0f + __expf(2.0f * x));
}

__device__ __forceinline__ half8 ld8w(const float* p) {
    floatx4 a = *(const floatx4*)p;
    floatx4 b = *(const floatx4*)(p + 4);
    half8 h;
    h[0] = (_Float16)a[0]; h[1] = (_Float16)a[1]; h[2] = (_Float16)a[2]; h[3] = (_Float16)a[3];
    h[4] = (_Float16)b[0]; h[5] = (_Float16)b[1]; h[6] = (_Float16)b[2]; h[7] = (_Float16)b[3];
    return h;
}

// FAST channel: sc0 both sides -> XCD-local L2 is producer/consumer meeting
// point (L1 bypassed / written through at XCD scope).
__device__ __forceinline__ void ld64_sc0(const void* p, u32x4& a, u32x4& b, u32x4& c, u32x4& d) {
    asm volatile(
        "global_load_dwordx4 %0, %4, off sc0\n\t"
        "global_load_dwordx4 %1, %4, off offset:16 sc0\n\t"
        "global_load_dwordx4 %2, %4, off offset:32 sc0\n\t"
        "global_load_dwordx4 %3, %4, off offset:48 sc0\n\t"
        "s_waitcnt vmcnt(0)"
        : "=&v"(a), "=&v"(b), "=&v"(c), "=&v"(d)
        : "v"(p)
        : "memory");
}
__device__ __forceinline__ void st16_sc0(void* p, u32x4 v) {
    asm volatile("global_store_dwordx4 %0, %1, off sc0" :: "v"(p), "v"(v) : "memory");
}
// SAFE channel: sc1 both sides -> device coherence point (v1-proven, works
// regardless of which XCDs the workers landed on).
__device__ __forceinline__ void ld64_sc1(const void* p, u32x4& a, u32x4& b, u32x4& c, u32x4& d) {
    asm volatile(
        "global_load_dwordx4 %0, %4, off sc1\n\t"
        "global_load_dwordx4 %1, %4, off offset:16 sc1\n\t"
        "global_load_dwordx4 %2, %4, off offset:32 sc1\n\t"
        "global_load_dwordx4 %3, %4, off offset:48 sc1\n\t"
        "s_waitcnt vmcnt(0)"
        : "=&v"(a), "=&v"(b), "=&v"(c), "=&v"(d)
        : "v"(p)
        : "memory");
}
__device__ __forceinline__ void st16_sc1(void* p, u32x4 v) {
    asm volatile("global_store_dwordx4 %0, %1, off sc1" :: "v"(p), "v"(v) : "memory");
}

__device__ __forceinline__ bool tags_ok(const u32x4& a, const u32x4& b,
                                        const u32x4& c, const u32x4& d, uint32_t want) {
    return a[1] == want && a[3] == want && b[1] == want && b[3] == want &&
           c[1] == want && c[3] == want && d[1] == want && d[3] == want;
}

// Ring slot layout (both rings): slot s at base + s*16384:
//   [16 rows][128 chunks x 8B]  chunk c = { f16 h[2c], f16 h[2c+1], u32 tag=t+1 }
// cnt[] (zeroed per launch): cnt[0..7] per-XCD claim tickets, cnt[8] = elected
// XCD + 1 (0 = none yet).
__global__ __launch_bounds__(256, 1) void lstm_kernel(
    const float* __restrict__ x0, const float* __restrict__ x1, const float* __restrict__ x2,
    const float* __restrict__ Wih_a, const float* __restrict__ Whh_a,
    const float* __restrict__ bih_a, const float* __restrict__ bhh_a,
    const float* __restrict__ Wih_b, const float* __restrict__ Whh_b,
    const float* __restrict__ bih_b, const float* __restrict__ bhh_b,
    const float* __restrict__ Wih_c, const float* __restrict__ Whh_c,
    const float* __restrict__ bih_c, const float* __restrict__ bhh_c,
    float* __restrict__ out, uint8_t* __restrict__ safering, uint8_t* __restrict__ fastring,
    uint32_t* __restrict__ cnt, int smaskS, int smaskF, int mode)
{
    const int tid = threadIdx.x;

    // ---- worker selection ----
    __shared__ int s_g;
    if (tid == 0) {
        int gg;
        if (mode != 0) {
            uint32_t xcc;
            asm volatile("s_getreg_b32 %0, hwreg(20, 0, 32)" : "=s"(xcc));  // HW_REG_XCC_ID
            xcc &= 7u;
            const uint32_t my = atomicAdd(&cnt[xcc], 1u);
            if (my == 15u) atomicCAS(&cnt[8], 0u, xcc + 1u);  // 16th claimant elects its XCD
            uint32_t ch;
            while ((ch = __hip_atomic_load(&cnt[8], __ATOMIC_RELAXED,
                                           __HIP_MEMORY_SCOPE_AGENT)) == 0u) {
                __builtin_amdgcn_s_sleep(8);
            }
            gg = (ch == xcc + 1u && my < 16u) ? (int)my : -1;
        } else {
            gg = (blockIdx.x < 16) ? (int)blockIdx.x : -1;  // pure-safe mode
        }
        s_g = gg;
    }
    __syncthreads();
    const int g = s_g;               // logical WG id 0..15
    if (g < 0) return;               // everyone else leaves

    const int w   = tid >> 6;        // wave 0..3
    const int l   = tid & 63;
    const int n   = l & 15;          // MFMA col (weights) / M row (activations)
    const int mg  = l >> 4;          // quad
    const int up  = n & 3;           // unit-within-wave
    const int gt  = n >> 2;          // gate: 0=i 1=f 2=g 3=o
    const int unit = g * 16 + w * 4 + up;
    const int R    = gt * 256 + unit;

    // LDS [x | h], row stride 520 halfs (1040B, 16B-aligned; bank shift 4 ->
    // only free 2-way conflicts on frag reads).
    __shared__ _Float16 XH[16][520];

    // ---- weights -> registers as B-fragments ----
    half8 wfa[16], wfb[12], wfc[10];
    {
        const int ko = mg * 8;
        #pragma unroll
        for (int kt = 0; kt < 8; ++kt) wfa[kt]     = ld8w(Wih_a + (size_t)R * 256 + kt * 32 + ko);
        #pragma unroll
        for (int kt = 0; kt < 8; ++kt) wfa[8 + kt] = ld8w(Whh_a + (size_t)R * 256 + kt * 32 + ko);
        #pragma unroll
        for (int kt = 0; kt < 4; ++kt) wfb[kt]     = ld8w(Wih_b + (size_t)R * 128 + kt * 32 + ko);
        #pragma unroll
        for (int kt = 0; kt < 8; ++kt) wfb[4 + kt] = ld8w(Whh_b + (size_t)R * 256 + kt * 32 + ko);
        #pragma unroll
        for (int kt = 0; kt < 2; ++kt) wfc[kt]     = ld8w(Wih_c + (size_t)R * 64  + kt * 32 + ko);
        #pragma unroll
        for (int kt = 0; kt < 8; ++kt) wfc[2 + kt] = ld8w(Whh_c + (size_t)R * 256 + kt * 32 + ko);
    }
    const float ba = bih_a[R] + bhh_a[R];
    const float bb = bih_b[R] + bhh_b[R];
    const float bc = bih_c[R] + bhh_c[R];

    float cst[4] = {0.f, 0.f, 0.f, 0.f};
    int useFast = (mode != 0);       // sticky per-thread: trips once, stays safe

    for (int t = 0; t < T_STEPS; ++t) {
        __syncthreads();   // prev step's LDS reads done before overwrite

        const int br = ((t & 3) == 0) ? 0 : (((t & 1) == 0) ? 1 : 2);
        const int kx = (br == 0) ? 256 : ((br == 1) ? 128 : 64);

        // ---- stage x (no h dependency; overlaps publish/visibility latency) ----
        if (tid < 128) {
            const int m = tid >> 3, cg = (tid & 7) * 8;
            *(half8*)&XH[m][cg] = ld8w(x0 + (size_t)t * 1024 + m * 64 + cg);
        } else if (br < 2) {
            const int tt = tid - 128;
            const int m = tt >> 3, cg = (tt & 7) * 8;
            *(half8*)&XH[m][64 + cg] = ld8w(x1 + (size_t)(t >> 1) * 1024 + m * 64 + cg);
        }
        if (br == 0) {
            const int m = tid >> 4, cg = (tid & 15) * 8;
            *(half8*)&XH[m][128 + cg] = ld8w(x2 + (size_t)(t >> 2) * 2048 + m * 128 + cg);
        }

        // ---- h(t-1): bounded fast poll (XCD L2), sticky safe fallback (MALL) ----
        {
            const int row = tid >> 4, u = tid & 15;
            _Float16* dst = &XH[row][kx + u * 16];
            if (t == 0) {
                *(u32x4*)dst       = (u32x4)0u;
                *(u32x4*)(dst + 8) = (u32x4)0u;
            } else {
                const uint32_t want = (uint32_t)t;   // h(t-1) was tagged (t-1)+1
                const size_t off = (size_t)row * 1024 + (size_t)u * 64;
                u32x4 a, b, c, d;
                bool got = false;
                if (useFast) {
                    const uint8_t* srcF = fastring + (size_t)((t - 1) & smaskF) * 16384 + off;
                    for (int i = 0; i < FASTN; ++i) {
                        ld64_sc0(srcF, a, b, c, d);
                        if (tags_ok(a, b, c, d, want)) { got = true; break; }
                    }
                    if (!got) useFast = 0;   // channel broken/straggling: go safe forever
                }
                if (!got) {
                    const uint8_t* srcS = safering + (size_t)((t - 1) & smaskS) * 16384 + off;
                    for (;;) {
                        ld64_sc1(srcS, a, b, c, d);
                        if (tags_ok(a, b, c, d, want)) break;
                    }
                }
                u32x4 lo = {a[0], a[2], b[0], b[2]};
                u32x4 hi = {c[0], c[2], d[0], d[2]};
                *(u32x4*)dst       = lo;
                *(u32x4*)(dst + 8) = hi;
            }
        }
        __syncthreads();

        // ---- gates = [x|h] @ W^T, two accumulators to halve MFMA dep chain ----
        floatx4 ac0 = {0.f, 0.f, 0.f, 0.f}, ac1 = {0.f, 0.f, 0.f, 0.f};
        {
            const int ao = mg * 8;
            if (br == 0) {
                #pragma unroll
                for (int kt = 0; kt < 16; kt += 2) {
                    ac0 = __builtin_amdgcn_mfma_f32_16x16x32_f16(
                        *(const half8*)&XH[n][kt * 32 + ao], wfa[kt], ac0, 0, 0, 0);
                    ac1 = __builtin_amdgcn_mfma_f32_16x16x32_f16(
                        *(const half8*)&XH[n][(kt + 1) * 32 + ao], wfa[kt + 1], ac1, 0, 0, 0);
                }
            } else if (br == 1) {
                #pragma unroll
                for (int kt = 0; kt < 12; kt += 2) {
                    ac0 = __builtin_amdgcn_mfma_f32_16x16x32_f16(
                        *(const half8*)&XH[n][kt * 32 + ao], wfb[kt], ac0, 0, 0, 0);
                    ac1 = __builtin_amdgcn_mfma_f32_16x16x32_f16(
                        *(const half8*)&XH[n][(kt + 1) * 32 + ao], wfb[kt + 1], ac1, 0, 0, 0);
                }
            } else {
                #pragma unroll
                for (int kt = 0; kt < 10; kt += 2) {
                    ac0 = __builtin_amdgcn_mfma_f32_16x16x32_f16(
                        *(const half8*)&XH[n][kt * 32 + ao], wfc[kt], ac0, 0, 0, 0);
                    ac1 = __builtin_amdgcn_mfma_f32_16x16x32_f16(
                        *(const half8*)&XH[n][(kt + 1) * 32 + ao], wfc[kt + 1], ac1, 0, 0, 0);
                }
            }
        }
        const floatx4 acc = ac0 + ac1;

        // ---- nonlinearity per-lane BEFORE gather (shortens post-shfl chain) ----
        const float bsel = (br == 0) ? ba : ((br == 1) ? bb : bc);
        float tv[4];
        #pragma unroll
        for (int r = 0; r < 4; ++r) {
            const float gv = acc[r] + bsel;
            tv[r] = (gt == 2) ? ftanh(gv) : fsig(gv);
        }
        float h2v[4];
        const int b0 = l & ~12;
        #pragma unroll
        for (int r = 0; r < 4; ++r) {
            const float vi = __shfl(tv[r], b0,      64);
            const float vf = __shfl(tv[r], b0 + 4,  64);
            const float vg = __shfl(tv[r], b0 + 8,  64);
            const float vo = __shfl(tv[r], b0 + 12, 64);
            const float c2 = vf * cst[r] + vi * vg;
            cst[r] = c2;
            h2v[r] = vo * ftanh(c2);
        }

        // ---- publish h(t): fast (sc0, XCD L2) then safe (sc1, MALL) ----
        {
            const size_t colb = (size_t)(8 * g + 2 * w) * 8;
            uint8_t* sbS = safering + (size_t)(t & smaskS) * 16384 + colb;
            uint8_t* sbF = fastring + (size_t)(t & smaskF) * 16384 + colb;
            const int s0 = l & ~15;
            #pragma unroll
            for (int r = 0; r < 4; ++r) {
                const unsigned hv =
                    (unsigned)__builtin_bit_cast(unsigned short, (_Float16)h2v[r]);
                const unsigned v0 = (unsigned)__shfl((int)hv, s0,     64);
                const unsigned v1 = (unsigned)__shfl((int)hv, s0 + 1, 64);
                const unsigned v2 = (unsigned)__shfl((int)hv, s0 + 2, 64);
                const unsigned v3 = (unsigned)__shfl((int)hv, s0 + 3, 64);
                if (n == 0) {
                    u32x4 pk = { (v0 & 0xffffu) | (v1 << 16), (unsigned)(t + 1),
                                 (v2 & 0xffffu) | (v3 << 16), (unsigned)(t + 1) };
                    if (mode != 0) st16_sc0(sbF + (size_t)(mg * 4 + r) * 1024, pk);
                    st16_sc1(sbS + (size_t)(mg * 4 + r) * 1024, pk);
                }
            }
        }

        // ---- store ys[t] fp32 (off critical path) ----
        if (gt == 0) {   // lanes with n == up hold their own h2v
            float* op = out + (size_t)t * 4096 + (size_t)(mg * 4) * 256 + unit;
            #pragma unroll
            for (int r = 0; r < 4; ++r) op[r * 256] = h2v[r];
        }
    }
}

extern "C" void kernel_launch(void* const* d_in, const int* in_sizes, int n_in,
                              void* d_out, int out_size, void* d_ws, size_t ws_size,
                              hipStream_t stream) {
    (void)in_sizes; (void)n_in; (void)out_size;
    uint8_t* ws = (uint8_t*)d_ws;
    int mode, smaskS, smaskF;
    size_t fast_off, cnt_off;
    if (ws_size >= (size_t)8 * 16384 + 64) {          // 4-slot safe + 4-slot fast + cnt
        mode = 1; smaskS = 3; smaskF = 3; fast_off = 4 * 16384; cnt_off = 8 * 16384;
    } else if (ws_size >= (size_t)4 * 16384 + 64) {   // 2-slot safe + 2-slot fast + cnt
        mode = 1; smaskS = 1; smaskF = 1; fast_off = 2 * 16384; cnt_off = 4 * 16384;
    } else {                                           // pure-safe fallback (v1 protocol)
        mode = 0; smaskS = (ws_size >= (size_t)4 * 16384) ? 3 : 1; smaskF = smaskS;
        fast_off = 0; cnt_off = 0;
    }
    if (mode != 0) {
        // zero claim counters (stream-ordered; harness's own reset() uses
        // hipMemsetAsync, so this is graph-capture legal)
        hipMemsetAsync(ws + cnt_off, 0, 64, stream);
    }
    hipLaunchKernelGGL(lstm_kernel, dim3(256), dim3(256), 0, stream,
        (const float*)d_in[0], (const float*)d_in[1], (const float*)d_in[2],
        (const float*)d_in[3], (const float*)d_in[4], (const float*)d_in[5], (const float*)d_in[6],
        (const float*)d_in[7], (const float*)d_in[8], (const float*)d_in[9], (const float*)d_in[10],
        (const float*)d_in[11], (const float*)d_in[12], (const float*)d_in[13], (const float*)d_in[14],
        (float*)d_out, ws, ws + fast_off,
        (uint32_t*)(ws + cnt_off), smaskS, smaskF, mode);
}

// Round 3
// 20014.809 us; speedup vs baseline: 1.3738x; 1.3738x over previous
//
#include <hip/hip_runtime.h>
#include <stdint.h>

// MultiRateLSTM on MI355X — persistent 16-WG kernel, fence-free h exchange.
//
// v4 = v1's proven sc1/MALL protocol (16 blocks, no election) + two serial-
// chain cuts identified from v1's counters (ring polls/step were only ~1.9;
// the step was dominated by the x HBM stall + full MFMA chain after detect):
//   1. x register-prefetch, double-buffered (sets A/B, statically named):
//      loads for x(t+2) issue mid-step t (right after poll success, so the
//      next vmcnt(0) drain is a full step away -> ~900cy HBM latency fully
//      hidden); convert+stage into LDS x-double-buffer at end of step t+1.
//   2. MFMA split around the poll: Wih*x part (no h dependency) runs BEFORE
//      the poll, absorbing publish-visibility latency; post-detect tail is
//      only the 8 Whh MFMAs + nonlin + shfl + publish. Frag->accumulator
//      assignment unchanged (bit-identical numerics).
// Tags are t+1 (never 0) so a zero-poisoned ring can't false-match at t=1.
//
// 16 WGs x 256 threads. WG g owns hidden units [16g,16g+16). Wave w owns units
// 16g+4w..+3 x all 4 gates (16 MFMA cols). Weights live in VGPRs/AGPRs as f16
// MFMA B-fragments (~152 regs/lane).

typedef _Float16 half8 __attribute__((ext_vector_type(8)));
typedef float floatx4 __attribute__((ext_vector_type(4)));
typedef unsigned int u32x4 __attribute__((ext_vector_type(4)));

#define T_STEPS 8192
#define NWG 16

__device__ __forceinline__ float fsig(float x) {
    return __builtin_amdgcn_rcpf(1.0f + __expf(-x));
}
__device__ __forceinline__ float ftanh(float x) {
    return 1.0f - 2.0f * __builtin_amdgcn_rcpf(1.0f + __expf(2.0f * x));
}

__device__ __forceinline__ half8 cvt8(floatx4 a, floatx4 b) {
    half8 h;
    h[0] = (_Float16)a[0]; h[1] = (_Float16)a[1]; h[2] = (_Float16)a[2]; h[3] = (_Float16)a[3];
    h[4] = (_Float16)b[0]; h[5] = (_Float16)b[1]; h[6] = (_Float16)b[2]; h[7] = (_Float16)b[3];
    return h;
}
__device__ __forceinline__ half8 ld8w(const float* p) {
    floatx4 a = *(const floatx4*)p;
    floatx4 b = *(const floatx4*)(p + 4);
    return cvt8(a, b);
}

// 64B agent-coherent load (bypasses non-coherent per-XCD L2), one vmcnt drain.
__device__ __forceinline__ void ld64_sc1(const void* p, u32x4& a, u32x4& b, u32x4& c, u32x4& d) {
    asm volatile(
        "global_load_dwordx4 %0, %4, off sc1\n\t"
        "global_load_dwordx4 %1, %4, off offset:16 sc1\n\t"
        "global_load_dwordx4 %2, %4, off offset:32 sc1\n\t"
        "global_load_dwordx4 %3, %4, off offset:48 sc1\n\t"
        "s_waitcnt vmcnt(0)"
        : "=&v"(a), "=&v"(b), "=&v"(c), "=&v"(d)
        : "v"(p)
        : "memory");
}
__device__ __forceinline__ void st16_sc1(void* p, u32x4 v) {
    asm volatile("global_store_dwordx4 %0, %1, off sc1" :: "v"(p), "v"(v) : "memory");
}

// ws ring: slot s (s = t & smask) at ws + s*16384:
//   [16 rows][128 chunks x 8B]  chunk c = { f16 h[2c], f16 h[2c+1], u32 tag=t+1 }
__global__ __launch_bounds__(256, 1) void lstm_kernel(
    const float* __restrict__ x0, const float* __restrict__ x1, const float* __restrict__ x2,
    const float* __restrict__ Wih_a, const float* __restrict__ Whh_a,
    const float* __restrict__ bih_a, const float* __restrict__ bhh_a,
    const float* __restrict__ Wih_b, const float* __restrict__ Whh_b,
    const float* __restrict__ bih_b, const float* __restrict__ bhh_b,
    const float* __restrict__ Wih_c, const float* __restrict__ Whh_c,
    const float* __restrict__ bih_c, const float* __restrict__ bhh_c,
    float* __restrict__ out, uint8_t* __restrict__ ws, int smask)
{
    const int tid = threadIdx.x;
    const int g   = blockIdx.x;      // 0..15
    const int w   = tid >> 6;        // wave 0..3
    const int l   = tid & 63;
    const int n   = l & 15;          // MFMA col (weights) / M row (activations)
    const int mg  = l >> 4;          // quad
    const int up  = n & 3;           // unit-within-wave
    const int gt  = n >> 2;          // gate: 0=i 1=f 2=g 3=o
    const int unit = g * 16 + w * 4 + up;
    const int R    = gt * 256 + unit;

    uint8_t* hring = ws;

    // LDS: x double-buffer + h buffer. Row stride 264 halfs (528B, 16B
    // aligned; 132 dwords == 4 mod 32 -> same free-2-way conflict profile as
    // v1's 520 stride).
    __shared__ _Float16 XB[2][16][264];
    __shared__ _Float16 HB[16][264];

    // ---- weights -> registers as B-fragments ----
    half8 wfa[16], wfb[12], wfc[10];
    {
        const int ko = mg * 8;
        #pragma unroll
        for (int kt = 0; kt < 8; ++kt) wfa[kt]     = ld8w(Wih_a + (size_t)R * 256 + kt * 32 + ko);
        #pragma unroll
        for (int kt = 0; kt < 8; ++kt) wfa[8 + kt] = ld8w(Whh_a + (size_t)R * 256 + kt * 32 + ko);
        #pragma unroll
        for (int kt = 0; kt < 4; ++kt) wfb[kt]     = ld8w(Wih_b + (size_t)R * 128 + kt * 32 + ko);
        #pragma unroll
        for (int kt = 0; kt < 8; ++kt) wfb[4 + kt] = ld8w(Whh_b + (size_t)R * 256 + kt * 32 + ko);
        #pragma unroll
        for (int kt = 0; kt < 2; ++kt) wfc[kt]     = ld8w(Wih_c + (size_t)R * 64  + kt * 32 + ko);
        #pragma unroll
        for (int kt = 0; kt < 8; ++kt) wfc[2 + kt] = ld8w(Whh_c + (size_t)R * 256 + kt * 32 + ko);
    }
    const float ba = bih_a[R] + bhh_a[R];
    const float bb = bih_b[R] + bhh_b[R];
    const float bc = bih_c[R] + bhh_c[R];

    // ---- x prefetch plumbing ----
    const int pm  = (tid & 127) >> 3;   // row for x0/x1 slice
    const int pcg = (tid & 7) * 8;      // col for x0/x1 slice
    const int qm  = tid >> 4;           // row for x2 slice
    const int qcg = (tid & 15) * 8;     // col for x2 slice

    floatx4 z4 = {0.f, 0.f, 0.f, 0.f};
    floatx4 a0A = z4, a1A = z4, b0A = z4, b1A = z4;   // prefetch set A (issued on even t)
    floatx4 a0B = z4, a1B = z4, b0B = z4, b1B = z4;   // prefetch set B (issued on odd t)

    auto issue = [&](int ts, floatx4& A0, floatx4& A1, floatx4& B0, floatx4& B1) {
        const int brn = ((ts & 3) == 0) ? 0 : (((ts & 1) == 0) ? 1 : 2);
        if (tid < 128) {
            const floatx4* s = (const floatx4*)(x0 + (size_t)ts * 1024 + pm * 64 + pcg);
            A0 = s[0]; A1 = s[1];
        } else if (brn < 2) {
            const floatx4* s = (const floatx4*)(x1 + (size_t)(ts >> 1) * 1024 + pm * 64 + pcg);
            A0 = s[0]; A1 = s[1];
        }
        if (brn == 0) {
            const floatx4* s = (const floatx4*)(x2 + (size_t)(ts >> 2) * 2048 + qm * 128 + qcg);
            B0 = s[0]; B1 = s[1];
        }
    };
    auto stage = [&](int ts, floatx4 A0, floatx4 A1, floatx4 B0, floatx4 B1) {
        const int brn = ((ts & 3) == 0) ? 0 : (((ts & 1) == 0) ? 1 : 2);
        const int xb  = ts & 1;
        if (tid < 128)     *(half8*)&XB[xb][pm][pcg]       = cvt8(A0, A1);
        else if (brn < 2)  *(half8*)&XB[xb][pm][64 + pcg]  = cvt8(A0, A1);
        if (brn == 0)      *(half8*)&XB[xb][qm][128 + qcg] = cvt8(B0, B1);
    };

    // prologue: x(0) staged directly; x(1) issued into set B
    {
        floatx4 A0 = z4, A1 = z4, B0 = z4, B1 = z4;
        issue(0, A0, A1, B0, B1);
        stage(0, A0, A1, B0, B1);
    }
    issue(1, a0B, a1B, b0B, b1B);

    float cst[4] = {0.f, 0.f, 0.f, 0.f};

    for (int t = 0; t < T_STEPS; ++t) {
        __syncthreads();   // (A) XB[t&1] writes visible; HB free for this step

        const int br = ((t & 3) == 0) ? 0 : (((t & 1) == 0) ? 1 : 2);
        const int ao = mg * 8;
        const int xb = t & 1;

        // ---- x-part MFMA (no h dependency; absorbs publish-visibility) ----
        floatx4 ac0 = {0.f, 0.f, 0.f, 0.f}, ac1 = {0.f, 0.f, 0.f, 0.f};
        if (br == 0) {
            #pragma unroll
            for (int kt = 0; kt < 8; kt += 2) {
                ac0 = __builtin_amdgcn_mfma_f32_16x16x32_f16(
                    *(const half8*)&XB[xb][n][kt * 32 + ao], wfa[kt], ac0, 0, 0, 0);
                ac1 = __builtin_amdgcn_mfma_f32_16x16x32_f16(
                    *(const half8*)&XB[xb][n][(kt + 1) * 32 + ao], wfa[kt + 1], ac1, 0, 0, 0);
            }
        } else if (br == 1) {
            #pragma unroll
            for (int kt = 0; kt < 4; kt += 2) {
                ac0 = __builtin_amdgcn_mfma_f32_16x16x32_f16(
                    *(const half8*)&XB[xb][n][kt * 32 + ao], wfb[kt], ac0, 0, 0, 0);
                ac1 = __builtin_amdgcn_mfma_f32_16x16x32_f16(
                    *(const half8*)&XB[xb][n][(kt + 1) * 32 + ao], wfb[kt + 1], ac1, 0, 0, 0);
            }
        } else {
            ac0 = __builtin_amdgcn_mfma_f32_16x16x32_f16(
                *(const half8*)&XB[xb][n][ao], wfc[0], ac0, 0, 0, 0);
            ac1 = __builtin_amdgcn_mfma_f32_16x16x32_f16(
                *(const half8*)&XB[xb][n][32 + ao], wfc[1], ac1, 0, 0, 0);
        }

        // ---- h(t-1): poll self-tagged chunks (sc1/MALL, v1-proven) ----
        {
            const int row = tid >> 4, u = tid & 15;
            _Float16* dst = &HB[row][u * 16];
            if (t == 0) {
                *(u32x4*)dst       = (u32x4)0u;
                *(u32x4*)(dst + 8) = (u32x4)0u;
            } else {
                const uint32_t want = (uint32_t)t;   // h(t-1) tagged (t-1)+1
                const uint8_t* src = hring + (size_t)((t - 1) & smask) * 16384
                                   + (size_t)row * 1024 + (size_t)u * 64;
                u32x4 a, b, c, d;
                for (;;) {
                    ld64_sc1(src, a, b, c, d);
                    if (a[1] == want && a[3] == want && b[1] == want && b[3] == want &&
                        c[1] == want && c[3] == want && d[1] == want && d[3] == want)
                        break;
                }
                u32x4 lo = {a[0], a[2], b[0], b[2]};
                u32x4 hi = {c[0], c[2], d[0], d[2]};
                *(u32x4*)dst       = lo;
                *(u32x4*)(dst + 8) = hi;
            }
        }

        // ---- prefetch issue x(t+2) NOW: next vmcnt(0) drain is a step away ----
        if (t + 2 < T_STEPS) {
            if ((t & 1) == 0) issue(t + 2, a0A, a1A, b0A, b1A);
            else              issue(t + 2, a0B, a1B, b0B, b1B);
        }

        __syncthreads();   // (B) HB staged

        // ---- h-part MFMA (same frag->acc assignment as v1: bit-identical) ----
        if (br == 0) {
            #pragma unroll
            for (int kt = 0; kt < 8; kt += 2) {
                ac0 = __builtin_amdgcn_mfma_f32_16x16x32_f16(
                    *(const half8*)&HB[n][kt * 32 + ao], wfa[8 + kt], ac0, 0, 0, 0);
                ac1 = __builtin_amdgcn_mfma_f32_16x16x32_f16(
                    *(const half8*)&HB[n][(kt + 1) * 32 + ao], wfa[9 + kt], ac1, 0, 0, 0);
            }
        } else if (br == 1) {
            #pragma unroll
            for (int kt = 0; kt < 8; kt += 2) {
                ac0 = __builtin_amdgcn_mfma_f32_16x16x32_f16(
                    *(const half8*)&HB[n][kt * 32 + ao], wfb[4 + kt], ac0, 0, 0, 0);
                ac1 = __builtin_amdgcn_mfma_f32_16x16x32_f16(
                    *(const half8*)&HB[n][(kt + 1) * 32 + ao], wfb[5 + kt], ac1, 0, 0, 0);
            }
        } else {
            #pragma unroll
            for (int kt = 0; kt < 8; kt += 2) {
                ac0 = __builtin_amdgcn_mfma_f32_16x16x32_f16(
                    *(const half8*)&HB[n][kt * 32 + ao], wfc[2 + kt], ac0, 0, 0, 0);
                ac1 = __builtin_amdgcn_mfma_f32_16x16x32_f16(
                    *(const half8*)&HB[n][(kt + 1) * 32 + ao], wfc[3 + kt], ac1, 0, 0, 0);
            }
        }
        const floatx4 acc = ac0 + ac1;

        // ---- nonlinearity per-lane BEFORE gather (shortens post-shfl chain) ----
        const float bsel = (br == 0) ? ba : ((br == 1) ? bb : bc);
        float tv[4];
        #pragma unroll
        for (int r = 0; r < 4; ++r) {
            const float gv = acc[r] + bsel;
            tv[r] = (gt == 2) ? ftanh(gv) : fsig(gv);
        }
        float h2v[4];
        const int b0 = l & ~12;
        #pragma unroll
        for (int r = 0; r < 4; ++r) {
            const float vi = __shfl(tv[r], b0,      64);
            const float vf = __shfl(tv[r], b0 + 4,  64);
            const float vg = __shfl(tv[r], b0 + 8,  64);
            const float vo = __shfl(tv[r], b0 + 12, 64);
            const float c2 = vf * cst[r] + vi * vg;
            cst[r] = c2;
            h2v[r] = vo * ftanh(c2);
        }

        // ---- publish h(t) FIRST (critical path): self-tagged sc1 chunks ----
        {
            uint8_t* sb = hring + (size_t)(t & smask) * 16384 + (size_t)(8 * g + 2 * w) * 8;
            const int s0 = l & ~15;
            #pragma unroll
            for (int r = 0; r < 4; ++r) {
                const unsigned hv =
                    (unsigned)__builtin_bit_cast(unsigned short, (_Float16)h2v[r]);
                const unsigned v0 = (unsigned)__shfl((int)hv, s0,     64);
                const unsigned v1 = (unsigned)__shfl((int)hv, s0 + 1, 64);
                const unsigned v2 = (unsigned)__shfl((int)hv, s0 + 2, 64);
                const unsigned v3 = (unsigned)__shfl((int)hv, s0 + 3, 64);
                if (n == 0) {
                    u32x4 pk = { (v0 & 0xffffu) | (v1 << 16), (unsigned)(t + 1),
                                 (v2 & 0xffffu) | (v3 << 16), (unsigned)(t + 1) };
                    st16_sc1(sb + (size_t)(mg * 4 + r) * 1024, pk);
                }
            }
        }

        // ---- store ys[t] fp32 (off critical path) ----
        if (gt == 0) {   // lanes with n == up hold their own h2v
            float* op = out + (size_t)t * 4096 + (size_t)(mg * 4) * 256 + unit;
            #pragma unroll
            for (int r = 0; r < 4; ++r) op[r * 256] = h2v[r];
        }

        // ---- stage x(t+1) into the other LDS buffer (off critical path) ----
        if (t + 1 < T_STEPS) {
            if (t & 1) stage(t + 1, a0A, a1A, b0A, b1A);
            else       stage(t + 1, a0B, a1B, b0B, b1B);
        }
    }
}

extern "C" void kernel_launch(void* const* d_in, const int* in_sizes, int n_in,
                              void* d_out, int out_size, void* d_ws, size_t ws_size,
                              hipStream_t stream) {
    (void)in_sizes; (void)n_in; (void)out_size;
    const int smask = (ws_size >= 4 * 16384) ? 3 : 1;   // ring slots: 4 (or 2 if ws tiny)
    hipLaunchKernelGGL(lstm_kernel, dim3(NWG), dim3(256), 0, stream,
        (const float*)d_in[0], (const float*)d_in[1], (const float*)d_in[2],
        (const float*)d_in[3], (const float*)d_in[4], (const float*)d_in[5], (const float*)d_in[6],
        (const float*)d_in[7], (const float*)d_in[8], (const float*)d_in[9], (const float*)d_in[10],
        (const float*)d_in[11], (const float*)d_in[12], (const float*)d_in[13], (const float*)d_in[14],
        (float*)d_out, (uint8_t*)d_ws, smask);
}